// Round 4
// baseline (250.500 us; speedup 1.0000x reference)
//
#include <hip/hip_runtime.h>
#include <hip/hip_bf16.h>
#include <stdint.h>

typedef unsigned short u16;
typedef __attribute__((ext_vector_type(8))) __bf16 bf16x8;
typedef __attribute__((ext_vector_type(4))) float f32x4;

#define C_DIM 768
#define HALF_C 384
#define N_SEQ 2048
#define BATCH 8
#define M_TOT (BATCH * N_SEQ) /* 16384 */
#define BK 32
#define NT (C_DIM / BK) /* 24 K-tiles */
// Block tile 128x256 (M x N), 8 waves (2 M x 4 N), per-wave 64x64 = acc[4][4].
// LDS: ring-3 of {A 128x32 (8 KB) + B 256x32 (16 KB)} = 72 KiB -> 2 blocks/CU.
// Per-slot u16 layout: A at +0 (4096), B at +4096 (8192); slot stride 12288.

__device__ __forceinline__ u16 f2bf(float f) {
    union { float f; unsigned u; } c; c.f = f;
    unsigned r = (c.u + 0x7FFFu + ((c.u >> 16) & 1u)) >> 16;
    return (u16)r;
}

// One fused prep launch:
//   blocks [0,12288)            : feature f32->bf16 (float4/ushort4)
//   blocks [12288,14592) x4     : the four 768x768 weights
//   blocks [14592,17664)        : packed (cos,sin) bf16x2 table [N_SEQ][HALF_C]
#define PREP_XBLK 12288
#define PREP_WBLK 576
#define PREP_SBLK 3072
__global__ __launch_bounds__(256) void prep_kernel(
    const float* __restrict__ feat,
    const float* __restrict__ Wq, const float* __restrict__ Wk,
    const float* __restrict__ Wqc, const float* __restrict__ Wkc,
    u16* __restrict__ xbf,
    u16* __restrict__ w0, u16* __restrict__ w1,
    u16* __restrict__ w2, u16* __restrict__ w3,
    uint32_t* __restrict__ cs_tab) {
    const int b = blockIdx.x, tid = threadIdx.x;
    if (b < PREP_XBLK + 4 * PREP_WBLK) {
        const float* src; u16* dst; int base;
        if (b < PREP_XBLK)                    { src = feat; dst = xbf; base = 0; }
        else if (b < PREP_XBLK + PREP_WBLK)   { src = Wq;  dst = w0; base = PREP_XBLK; }
        else if (b < PREP_XBLK + 2*PREP_WBLK) { src = Wk;  dst = w1; base = PREP_XBLK + PREP_WBLK; }
        else if (b < PREP_XBLK + 3*PREP_WBLK) { src = Wqc; dst = w2; base = PREP_XBLK + 2*PREP_WBLK; }
        else                                  { src = Wkc; dst = w3; base = PREP_XBLK + 3*PREP_WBLK; }
        const int i = (b - base) * 256 + tid;
        float4 v = ((const float4*)src)[i];
        ushort4 o;
        o.x = f2bf(v.x); o.y = f2bf(v.y); o.z = f2bf(v.z); o.w = f2bf(v.w);
        ((ushort4*)dst)[i] = o;
    } else {
        const int idx = (b - PREP_XBLK - 4 * PREP_WBLK) * 256 + tid; // < N_SEQ*HALF_C
        const int pos = idx / HALF_C;
        const int ip  = idx - pos * HALF_C;
        float inv = powf(10000.0f, (-2.0f / (float)C_DIM) * (float)ip);
        float ang = (float)pos * inv;
        uint32_t c = f2bf(cosf(ang)), s = f2bf(sinf(ang));
        cs_tab[idx] = (s << 16) | c;   // low = cos, high = sin
    }
}

template<int N> __device__ __forceinline__ void vmwait();
template<> __device__ __forceinline__ void vmwait<3>() { asm volatile("s_waitcnt vmcnt(3)" ::: "memory"); }
template<> __device__ __forceinline__ void vmwait<0>() { asm volatile("s_waitcnt vmcnt(0)" ::: "memory"); }

__device__ __forceinline__ void async_load16(const void* src, void* dst_lds) {
    const __attribute__((address_space(1))) void* g =
        (const __attribute__((address_space(1))) void*)(uintptr_t)src;
    __attribute__((address_space(3))) void* l =
        (__attribute__((address_space(3))) void*)(unsigned)(uintptr_t)dst_lds;
    __builtin_amdgcn_global_load_lds(g, l, 16, 0, 0);
}

// Stage a NROWS x 32 bf16 operand K-tile into LDS (linear dest, gload_lds).
// Bank-conflict swizzle via permuted per-lane GLOBAL source (m173 pattern):
// logical (row m, k-slot s) lives at physical slot s ^ ((m>>2)&3).
// Writer: phys slot = lane&3, row-quad = (lane>>4)&3 -> fetch logical slot
// (lane&3)^((lane>>4)&3). NROWS=128: 1 load/lane; NROWS=256: 2 loads/lane.
template<int NROWS>
__device__ __forceinline__ void stageT(const u16* __restrict__ g, int ld,
                                       u16* ldsbase, int wave, int lane) {
    const int s  = (lane & 3) ^ ((lane >> 4) & 3);
    const int rr = lane >> 2;  // row within 16-row chunk
    #pragma unroll
    for (int j = 0; j < NROWS / 128; ++j) {
        const int chunk = wave + j * 8;
        const u16* src = g + (size_t)(chunk * 16 + rr) * ld + s * 8;
        async_load16(src, ldsbase + chunk * 512);  // wave-uniform dst
    }
}

// acc[4][4] += A[128,768] x B[256,768]^T slice for this wave (64x64).
// Ring-3: compute tile t from slot t%3 while tile t+2 streams into (t+2)%3
// (that slot's reads finished at end of tile t-1). Boundary wait vmcnt(3)
// keeps tile t+2's 3 loads in flight; drain-0 only at the tail.
__device__ __forceinline__ void gemm_mainloop(
    const u16* __restrict__ A, const u16* __restrict__ B, int ld,
    u16* Lds, f32x4 (&acc)[4][4], int wave, int lane) {

    stageT<128>(A, ld, Lds, wave, lane);
    stageT<256>(B, ld, Lds + 4096, wave, lane);
    stageT<128>(A + BK, ld, Lds + 12288, wave, lane);
    stageT<256>(B + BK, ld, Lds + 12288 + 4096, wave, lane);
    __builtin_amdgcn_sched_barrier(0);
    vmwait<3>();   // tile 0 landed; tile 1 in flight
    __builtin_amdgcn_s_barrier();
    __builtin_amdgcn_sched_barrier(0);

    const int r = lane & 15, sl = lane >> 4;
    // reader-side swizzle: phys slot = sl ^ ((r>>2)&3)
    const int lane_off = r * 32 + ((sl ^ ((r >> 2) & 3)) * 8);
    const int wm = wave >> 2, wn = wave & 3;
    const int a_base = lane_off + wm * 2048;          // A rows wm*64.., frag stride 512
    const int b_base = 4096 + lane_off + wn * 2048;   // B rows wn*64.., frag stride 512

    #pragma unroll
    for (int t = 0; t < NT; ++t) {
        const u16* S = Lds + (t % 3) * 12288;
        if (t + 2 < NT) {
            u16* D = Lds + ((t + 2) % 3) * 12288;
            stageT<128>(A + (t + 2) * BK, ld, D, wave, lane);
            stageT<256>(B + (t + 2) * BK, ld, D + 4096, wave, lane);
        }
        bf16x8 a[4], b[4];
        #pragma unroll
        for (int mf = 0; mf < 4; ++mf) a[mf] = *(const bf16x8*)(S + a_base + mf * 512);
        #pragma unroll
        for (int nf = 0; nf < 4; ++nf) b[nf] = *(const bf16x8*)(S + b_base + nf * 512);
        __builtin_amdgcn_sched_barrier(0);
        __builtin_amdgcn_s_barrier();       // phase-align: all waves enter MFMA together
        __builtin_amdgcn_sched_barrier(0);
        __builtin_amdgcn_s_setprio(1);
        #pragma unroll
        for (int mf = 0; mf < 4; ++mf)
            #pragma unroll
            for (int nf = 0; nf < 4; ++nf)
                acc[mf][nf] = __builtin_amdgcn_mfma_f32_16x16x32_bf16(a[mf], b[nf], acc[mf][nf], 0, 0, 0);
        __builtin_amdgcn_s_setprio(0);
        __builtin_amdgcn_sched_barrier(0);
        if (t < NT - 2)       vmwait<3>();  // tile t+1 landed, t+2 stays in flight
        else if (t == NT - 2) vmwait<0>();  // drain tail
        __builtin_amdgcn_s_barrier();       // tile boundary: slot (t+2)%3 now valid
        __builtin_amdgcn_sched_barrier(0);
    }
}

// out[m,d] = RoPE(x @ W^T + bias) as bf16; z selects projection. XCD-swizzled 1D grid.
__global__ __launch_bounds__(512, 4) void proj_kernel(
    const u16* __restrict__ xbf,
    const u16* __restrict__ W0, const u16* __restrict__ W1,
    const u16* __restrict__ W2, const u16* __restrict__ W3,
    const float* __restrict__ b0, const float* __restrict__ b1,
    const float* __restrict__ b2, const float* __restrict__ b3,
    u16* __restrict__ o0, u16* __restrict__ o1, u16* __restrict__ o2, u16* __restrict__ o3,
    const uint32_t* __restrict__ cs_tab) {
    __shared__ __align__(16) u16 Lds[3 * 12288];
    const int tid = threadIdx.x, lane = tid & 63, wave = tid >> 6;
    // grid = 1536: each XCD gets 192 contiguous logical blocks (half a z slice)
    const int bid = blockIdx.x;
    const int swz = (bid & 7) * 192 + (bid >> 3);
    const int z   = swz / 384;
    const int rem = swz % 384;
    const int by  = rem / 128;   // n-block (0..2)
    const int bx  = rem % 128;   // m-block
    const int m0 = bx * 128, n0 = by * 256;

    const u16*   W    = z == 0 ? W0 : z == 1 ? W1 : z == 2 ? W2 : W3;
    const float* bias = z == 0 ? b0 : z == 1 ? b1 : z == 2 ? b2 : b3;
    u16*         outp = z == 0 ? o0 : z == 1 ? o1 : z == 2 ? o2 : o3;

    f32x4 acc[4][4];
    #pragma unroll
    for (int x = 0; x < 4; ++x)
        #pragma unroll
        for (int y = 0; y < 4; ++y) acc[x][y] = f32x4{0.f, 0.f, 0.f, 0.f};

    gemm_mainloop(xbf + (size_t)m0 * C_DIM, W + (size_t)n0 * C_DIM, C_DIM,
                  Lds, acc, wave, lane);

    const int wm = wave >> 2, wn = wave & 3;
    const int g = lane >> 4, r = lane & 15;
    #pragma unroll
    for (int nf = 0; nf < 4; ++nf) {
        const int col = n0 + wn * 64 + nf * 16 + r;
        const float bv = bias[col];
        const int ip = col >> 1;
        const float sgn = (col & 1) ? 1.0f : -1.0f;  // even d: -x_odd*sin ; odd d: +x_even*sin
        #pragma unroll
        for (int mf = 0; mf < 4; ++mf) {
            #pragma unroll
            for (int i = 0; i < 4; ++i) {
                const int row = m0 + wm * 64 + mf * 16 + g * 4 + i;
                const int pos = row & (N_SEQ - 1);
                float v = acc[mf][nf][i] + bv;
                float p = __shfl_xor(v, 1);  // RoPE partner (col parity == lane parity)
                const uint32_t cs = cs_tab[pos * HALF_C + ip];
                const float c = __uint_as_float(cs << 16);
                const float s = __uint_as_float(cs & 0xFFFF0000u);
                outp[(size_t)row * C_DIM + col] = f2bf(v * c + sgn * p * s);
            }
        }
    }
}

// out[z,n,m] = (Q[z,n,:].K[z,m,:])/sqrt(C) - (m<n)*1e10/sqrt(C);  z = h*8+b.
// Fully-masked 128x256 blocks (mcol0+256 <= nrow0): write the constant, skip GEMM.
__global__ __launch_bounds__(512, 4) void logits_kernel(
    const u16* __restrict__ Q0, const u16* __restrict__ K0,
    const u16* __restrict__ Q1, const u16* __restrict__ K1,
    float* __restrict__ out) {
    __shared__ __align__(16) u16 Lds[3 * 12288];
    const int tid = threadIdx.x, lane = tid & 63, wave = tid >> 6;
    // grid = 2048: each XCD gets 256 contiguous = 2 full (h,b) slices
    const int bid = blockIdx.x;
    const int swz = (bid & 7) * 256 + (bid >> 3);
    const int z   = swz >> 7;          // 0..15 = h*8+b
    const int rem = swz & 127;
    const int by  = rem >> 3;          // row (Q) block, 0..15 (128 rows each)
    const int bx  = rem & 7;           // col (K) block, 0..7  (256 cols each)
    const int nrow0 = by * 128, mcol0 = bx * 256;

    const float RS = 0.036084391824351613f;  // 1/sqrt(768)
    const float MV = 1.0e10f * RS;
    float* outz = out + (size_t)z * N_SEQ * N_SEQ;

    if (mcol0 + 256 <= nrow0) {  // fully masked: |qk|*RS ~ 5 << threshold 7.2e6
        const float4 cv = {-MV, -MV, -MV, -MV};
        #pragma unroll
        for (int i = 0; i < 16; ++i) {
            const int row = nrow0 + wave * 16 + i;
            *(float4*)(outz + (size_t)row * N_SEQ + mcol0 + lane * 4) = cv;
        }
        return;
    }

    const int h = z >> 3, b = z & 7;
    const u16* Qb = (h ? Q1 : Q0) + (size_t)b * N_SEQ * C_DIM;
    const u16* Kb = (h ? K1 : K0) + (size_t)b * N_SEQ * C_DIM;

    f32x4 acc[4][4];
    #pragma unroll
    for (int x = 0; x < 4; ++x)
        #pragma unroll
        for (int y = 0; y < 4; ++y) acc[x][y] = f32x4{0.f, 0.f, 0.f, 0.f};

    gemm_mainloop(Qb + (size_t)nrow0 * C_DIM, Kb + (size_t)mcol0 * C_DIM, C_DIM,
                  Lds, acc, wave, lane);

    const int wm = wave >> 2, wn = wave & 3;
    const int g = lane >> 4, r = lane & 15;
    #pragma unroll
    for (int mf = 0; mf < 4; ++mf) {
        #pragma unroll
        for (int i = 0; i < 4; ++i) {
            const int row = nrow0 + wm * 64 + mf * 16 + g * 4 + i;
            float* orow = outz + (size_t)row * N_SEQ;
            #pragma unroll
            for (int nf = 0; nf < 4; ++nf) {
                const int col = mcol0 + wn * 64 + nf * 16 + r;
                orow[col] = acc[mf][nf][i] * RS - (col < row ? MV : 0.0f);
            }
        }
    }
}

extern "C" void kernel_launch(void* const* d_in, const int* in_sizes, int n_in,
                              void* d_out, int out_size, void* d_ws, size_t ws_size,
                              hipStream_t stream) {
    (void)in_sizes; (void)n_in; (void)out_size; (void)ws_size;
    const float* feat = (const float*)d_in[0];
    const float* Wq   = (const float*)d_in[1];
    const float* bq   = (const float*)d_in[2];
    const float* Wk   = (const float*)d_in[3];
    const float* bk   = (const float*)d_in[4];
    const float* Wqc  = (const float*)d_in[5];
    const float* bqc  = (const float*)d_in[6];
    const float* Wkc  = (const float*)d_in[7];
    const float* bkc  = (const float*)d_in[8];
    float* out = (float*)d_out;

    // workspace layout (u16 elements): x_bf | W_bf[4] | Q0 K0 Q1 K1 | cs_tab (u32)
    u16* ws = (u16*)d_ws;
    const size_t XE = (size_t)M_TOT * C_DIM;   // 12,582,912
    const size_t WE = (size_t)C_DIM * C_DIM;   // 589,824
    u16* xbf = ws;
    u16* Wb0 = ws + XE;
    u16* Wb1 = Wb0 + WE;
    u16* Wb2 = Wb1 + WE;
    u16* Wb3 = Wb2 + WE;
    u16* qkbase = Wb3 + WE;
    u16* Qa = qkbase;            // proj0: Wq
    u16* Ka = qkbase + XE;       // proj1: Wk
    u16* Qc = qkbase + 2 * XE;   // proj2: Wq_cls
    u16* Kc = qkbase + 3 * XE;   // proj3: Wk_cls
    uint32_t* cs_tab = (uint32_t*)(qkbase + 4 * XE);

    prep_kernel<<<dim3(PREP_XBLK + 4 * PREP_WBLK + PREP_SBLK), dim3(256), 0, stream>>>(
        feat, Wq, Wk, Wqc, Wkc, xbf, Wb0, Wb1, Wb2, Wb3, cs_tab);

    proj_kernel<<<dim3(1536), dim3(512), 0, stream>>>(
        xbf, Wb0, Wb1, Wb2, Wb3, bq, bk, bqc, bkc, Qa, Ka, Qc, Kc, cs_tab);

    logits_kernel<<<dim3(2048), dim3(512), 0, stream>>>(
        Qa, Ka, Qc, Kc, out);
}